// Round 7
// baseline (205.080 us; speedup 1.0000x reference)
//
#include <hip/hip_runtime.h>
#include <cstdint>

// ---- types ----
typedef __bf16 bf16;
typedef __attribute__((ext_vector_type(8))) __bf16 bf16x8;
typedef __attribute__((ext_vector_type(4))) __bf16 bf16v4;
typedef __attribute__((ext_vector_type(4))) float f32x4;
typedef __attribute__((ext_vector_type(16))) float f32x16;

#define MFMA16(a, b, c) __builtin_amdgcn_mfma_f32_16x16x32_bf16((a), (b), (c), 0, 0, 0)
#define MFMA32(a, b, c) __builtin_amdgcn_mfma_f32_32x32x16_bf16((a), (b), (c), 0, 0, 0)

// Problem constants
#define BATCH 2
#define SLEN 2048
#define HDIM 1024
#define NHEAD 16
#define HEADD 64
#define MROWS (BATCH * SLEN)   // 4096

#define CEXP 0.1803368801f     // 0.125 * log2(e), folded into Q at projection

// async global->LDS, 16B per lane. LDS dest is wave-uniform base + lane*16.
typedef __attribute__((address_space(3))) void lds_void;
typedef const __attribute__((address_space(1))) void glb_void;
__device__ __forceinline__ void load_lds16(const bf16* g, bf16* l) {
    __builtin_amdgcn_global_load_lds((glb_void*)g, (lds_void*)l, 16, 0, 0);
}

// ---------------------------------------------------------------------------
// merged prep kernel: one launch instead of five.
// ---------------------------------------------------------------------------
__global__ __launch_bounds__(256) void prep_kernel(const float* __restrict__ X,
                                                   const float* __restrict__ Wq,
                                                   const float* __restrict__ Wkv,
                                                   const float* __restrict__ Wo,
                                                   const float* __restrict__ bq,
                                                   const float* __restrict__ bkv,
                                                   bf16* __restrict__ Xbf,
                                                   bf16* __restrict__ WqkvT,
                                                   bf16* __restrict__ WoT,
                                                   float* __restrict__ bqkv) {
    const int blk = blockIdx.x;
    const int tid = threadIdx.x;
    if (blk < 4096) {
        int i = (blk * 256 + tid) * 4;
        float4 v = *(const float4*)&X[i];
        bf16v4 o;
        o[0] = (bf16)v.x; o[1] = (bf16)v.y; o[2] = (bf16)v.z; o[3] = (bf16)v.w;
        *(bf16v4*)&Xbf[i] = o;
        return;
    }
    if (blk < 8192) {
        const float* in; bf16* out; int C, id;
        if (blk < 5120)      { in = Wq;  out = WqkvT;                C = 1024; id = blk - 4096; }
        else if (blk < 7168) { in = Wkv; out = WqkvT + 1024 * 1024;  C = 2048; id = blk - 5120; }
        else                 { in = Wo;  out = WoT;                  C = 1024; id = blk - 7168; }
        const int R = 1024;
        const int nbx = C / 32;
        const int j0 = (id % nbx) * 32, i0 = (id / nbx) * 32;
        const int tx = tid & 31, ty = tid >> 5;
        __shared__ float t[32][33];
        for (int r = ty; r < 32; r += 8)
            t[r][tx] = in[(size_t)(i0 + r) * C + j0 + tx];
        __syncthreads();
        for (int r = ty; r < 32; r += 8)
            out[(size_t)(j0 + r) * R + i0 + tx] = (bf16)t[tx][r];
        return;
    }
    int i = (blk - 8192) * 256 + tid;
    if (i < 3072) bqkv[i] = (i < 1024) ? bq[i] : bkv[i - 1024];
}

// ---------------------------------------------------------------------------
// GEMM (m97-style): C[m][n] = sum_k A[m][k]*BT[n][k] + bias[n]
// EPI==1 (N=3072): Q pre-scaled by CEXP; K row-major; V transposed per head.
// EPI==2: write fp32 (out-projection).
// ---------------------------------------------------------------------------
template <int BM, int BN, int EPI>
__global__ __launch_bounds__(256) void gemm2_kernel(const bf16* __restrict__ A,
                                                    const bf16* __restrict__ BT,
                                                    const float* __restrict__ bias,
                                                    bf16* __restrict__ oQ,
                                                    bf16* __restrict__ oK,
                                                    bf16* __restrict__ oVT,
                                                    float* __restrict__ oF, int K) {
    constexpr int WM = BM / 2, WN = BN / 2;
    constexpr int MT = WM / 16, NT = WN / 16;

    const int tid = threadIdx.x;
    const int lane = tid & 63, wid = tid >> 6;
    const int l15 = lane & 15, quad = lane >> 4;
    const int wm = (wid >> 1) * WM, wn = (wid & 1) * WN;
    const int m0 = blockIdx.y * BM, n0 = blockIdx.x * BN;

    __shared__ bf16 As[BM * 32];
    __shared__ bf16 Bs[BN * 32];

    f32x4 acc[MT][NT] = {};

    const bf16* Ag = A + (size_t)m0 * K;
    const bf16* Bg = BT + (size_t)n0 * K;
    const int arow = lane >> 2, acol = (lane & 3) * 8;

    for (int k0 = 0; k0 < K; k0 += 32) {
#pragma unroll
        for (int t = 0; t < BM / 64; ++t) {
            int tt = t * 4 + wid;
            load_lds16(Ag + (size_t)(tt * 16 + arow) * K + k0 + acol, &As[tt * 512]);
        }
#pragma unroll
        for (int t = 0; t < BN / 64; ++t) {
            int tt = t * 4 + wid;
            load_lds16(Bg + (size_t)(tt * 16 + arow) * K + k0 + acol, &Bs[tt * 512]);
        }
        __syncthreads();

        bf16x8 af[MT], bfr[NT];
#pragma unroll
        for (int i = 0; i < MT; ++i)
            af[i] = *(const bf16x8*)&As[(wm + i * 16 + l15) * 32 + quad * 8];
#pragma unroll
        for (int j = 0; j < NT; ++j)
            bfr[j] = *(const bf16x8*)&Bs[(wn + j * 16 + l15) * 32 + quad * 8];
#pragma unroll
        for (int i = 0; i < MT; ++i)
#pragma unroll
            for (int j = 0; j < NT; ++j)
                acc[i][j] = MFMA16(af[i], bfr[j], acc[i][j]);
        __syncthreads();
    }

    // epilogue (C-layout: row = quad*4+r, col = l15)
#pragma unroll
    for (int i = 0; i < MT; ++i) {
#pragma unroll
        for (int j = 0; j < NT; ++j) {
            const int mb = m0 + wm + i * 16 + quad * 4;
            const int n = n0 + wn + j * 16 + l15;
            const float bv = bias[n];
            if (EPI == 2) {
                float* o = oF + (size_t)mb * 1024 + n;
#pragma unroll
                for (int r = 0; r < 4; ++r) o[(size_t)r * 1024] = acc[i][j][r] + bv;
            } else if (n0 < 1024) {
#pragma unroll
                for (int r = 0; r < 4; ++r)
                    oQ[(size_t)(mb + r) * 1024 + n] = (bf16)((acc[i][j][r] + bv) * CEXP);
            } else if (n0 < 2048) {
#pragma unroll
                for (int r = 0; r < 4; ++r)
                    oK[(size_t)(mb + r) * 1024 + (n - 1024)] = (bf16)(acc[i][j][r] + bv);
            } else {
                const int hd = n - 2048;
                const int bb = mb >> 11, ss = mb & 2047;
                bf16v4 pk;
#pragma unroll
                for (int r = 0; r < 4; ++r) pk[r] = (bf16)(acc[i][j][r] + bv);
                *(bf16v4*)&oVT[((size_t)(bb << 10) + hd) * 2048 + ss] = pk;
            }
        }
    }
}

// ---------------------------------------------------------------------------
// Flash attention v7: TLP version.
// 1024 blocks (xcd-swizzled: xcd owns 4 bh x 32 q-tiles of 64q), 4 blocks/CU,
// 16 waves/CU. block 256 = 4 waves: qgroup=wid&1 (32 queries), khalf=wid>>1
// (64 keys of each 128-key tile). Unnormalized softmax => khalf partials
// combine by simple addition at the end (no running max).
// P C-layout -> A-layout via 2x shfl_xor(32) per kstep (no Ps LDS buffer):
//   own quad = sacc regs 8(s&1)+4hh..+3; partner quad arrives key-ascending.
// LDS = Ks 16KB + VTs 16KB = 32KB; epilogue reuses it for pair-combine.
// ---------------------------------------------------------------------------
__global__ __launch_bounds__(256, 4) void attn7_kernel(const bf16* __restrict__ Q,
                                                       const bf16* __restrict__ K,
                                                       const bf16* __restrict__ VT,
                                                       bf16* __restrict__ O) {
    const int bid = blockIdx.x;
    const int xcd = bid & 7, j = bid >> 3;
    const int bh = xcd * 4 + (j >> 5);
    const int q0 = (j & 31) * 64;
    const int b = bh >> 4, head = bh & 15;
    const int tid = threadIdx.x;
    const int lane = tid & 63, wid = tid >> 6;
    const int l31 = lane & 31, hh = lane >> 5;
    const int qgroup = wid & 1, khalf = wid >> 1;

    __shared__ union SMem {
        struct { bf16 Ks[128 * 64]; bf16 VTs[64 * 128]; } t;
        float Xs[8192];
    } sm;
    bf16* Ks = sm.t.Ks;
    bf16* VTs = sm.t.VTs;

    // Q B-frags (32x32x16): n = l31, k = kd*16 + hh*8 + j
    const int qw = q0 + qgroup * 32;
    bf16x8 qf[4];
#pragma unroll
    for (int kd = 0; kd < 4; ++kd)
        qf[kd] = *(const bf16x8*)&Q[(size_t)(b * SLEN + qw + l31) * HDIM +
                                    head * 64 + kd * 16 + hh * 8];

    f32x16 o_acc[2] = {};
    float lp0 = 0.f, lp1 = 0.f, lp2 = 0.f, lp3 = 0.f;

    const bf16* Kg = K + (size_t)b * SLEN * HDIM + head * 64;
    const bf16* Vg = VT + (size_t)bh * 64 * SLEN;

    // staging lane geometry
    const int r8 = lane >> 3, p8 = lane & 7;     // K: 8 rows x 8 chunks / instr
    const int r16 = lane >> 4, p16 = lane & 15;  // V: 4 rows x 16 chunks / instr
    const int kb = khalf * 64;
    const int sw7 = l31 & 7, sw15 = l31 & 15;

    for (int kt = 0; kt < 16; ++kt) {
        const int k0 = kt * 128;
#pragma unroll
        for (int pass = 0; pass < 4; ++pass) {
            const int rbk = pass * 32 + wid * 8;
            load_lds16(Kg + (size_t)(k0 + rbk + r8) * HDIM + ((p8 ^ ((rbk + r8) & 7)) * 8),
                       &Ks[rbk * 64]);
            const int rbv = pass * 16 + wid * 4;
            load_lds16(Vg + (size_t)(rbv + r16) * SLEN + k0 + ((p16 ^ ((rbv + r16) & 15)) * 8),
                       &VTs[rbv * 128]);
        }
        __syncthreads();

        // S^T over this wave's 64-key half: 2 key-subtiles x 4 d-steps
        f32x16 sacc[2] = {};
#pragma unroll
        for (int kd = 0; kd < 4; ++kd)
#pragma unroll
            for (int m = 0; m < 2; ++m) {
                const int key = kb + m * 32 + l31;
                const int c = (kd * 2 + hh) ^ sw7;
                bf16x8 kf = *(const bf16x8*)&Ks[key * 64 + c * 8];
                sacc[m] = MFMA32(kf, qf[kd], sacc[m]);
            }

        // exp in place + partial l sums (4-way to shorten dep chain)
#pragma unroll
        for (int m = 0; m < 2; ++m)
#pragma unroll
            for (int g = 0; g < 4; ++g) {
                float p0 = __builtin_amdgcn_exp2f(sacc[m][g * 4 + 0]);
                float p1 = __builtin_amdgcn_exp2f(sacc[m][g * 4 + 1]);
                float p2 = __builtin_amdgcn_exp2f(sacc[m][g * 4 + 2]);
                float p3 = __builtin_amdgcn_exp2f(sacc[m][g * 4 + 3]);
                lp0 += p0; lp1 += p1; lp2 += p2; lp3 += p3;
                sacc[m][g * 4 + 0] = p0; sacc[m][g * 4 + 1] = p1;
                sacc[m][g * 4 + 2] = p2; sacc[m][g * 4 + 3] = p3;
            }

        // PV: per 16-key kstep, build P A-frag via shfl exchange, then MFMA
#pragma unroll
        for (int s = 0; s < 4; ++s) {
            const int m = s >> 1, base = 8 * (s & 1);
            bf16v4 lo4, hi4;
#pragma unroll
            for (int r = 0; r < 4; ++r) {
                lo4[r] = (bf16)sacc[m][base + r];
                hi4[r] = (bf16)sacc[m][base + 4 + r];
            }
            uint2 lo = __builtin_bit_cast(uint2, lo4);
            uint2 hi = __builtin_bit_cast(uint2, hi4);
            unsigned s0 = hh ? lo.x : hi.x;
            unsigned s1 = hh ? lo.y : hi.y;
            unsigned r0 = __shfl_xor(s0, 32, 64);
            unsigned r1 = __shfl_xor(s1, 32, 64);
            uint4 f;
            f.x = hh ? r0 : lo.x;
            f.y = hh ? r1 : lo.y;
            f.z = hh ? hi.x : r0;
            f.w = hh ? hi.y : r1;
            bf16x8 pf = __builtin_bit_cast(bf16x8, f);
#pragma unroll
            for (int dt = 0; dt < 2; ++dt) {
                const int d = dt * 32 + l31;
                const int cc = (khalf * 8 + s * 2 + hh) ^ sw15;
                bf16x8 vf = *(const bf16x8*)&VTs[d * 128 + cc * 8];
                o_acc[dt] = MFMA32(vf, pf, o_acc[dt]);
            }
        }
        __syncthreads();
    }

    // l for this wave's key-half (both hh halves)
    float l_lane = (lp0 + lp1) + (lp2 + lp3);
    l_lane += __shfl_xor(l_lane, 32, 64);

    // combine khalf pairs via LDS (reuse union; 4672 floats <= 8192)
    float* Xs = sm.Xs;
    if (khalf == 1) {
        float* w = Xs + qgroup * 2304 + lane * 36;
#pragma unroll
        for (int mt = 0; mt < 2; ++mt)
#pragma unroll
            for (int g = 0; g < 4; ++g) {
                f32x4 v = {o_acc[mt][g * 4 + 0], o_acc[mt][g * 4 + 1],
                           o_acc[mt][g * 4 + 2], o_acc[mt][g * 4 + 3]};
                *(f32x4*)&w[mt * 16 + g * 4] = v;
            }
        if (hh == 0) Xs[4608 + qgroup * 32 + l31] = l_lane;
    }
    __syncthreads();
    if (khalf == 0) {
        const float* w = Xs + qgroup * 2304 + lane * 36;
        const float l_full = l_lane + Xs[4608 + qgroup * 32 + l31];
        const float inv = 1.f / l_full;
        bf16* orow = O + (size_t)(b * SLEN + qw + l31) * HDIM + head * 64;
#pragma unroll
        for (int mt = 0; mt < 2; ++mt)
#pragma unroll
            for (int g = 0; g < 4; ++g) {
                f32x4 v = *(const f32x4*)&w[mt * 16 + g * 4];
                bf16v4 pk;
#pragma unroll
                for (int r = 0; r < 4; ++r)
                    pk[r] = (bf16)((o_acc[mt][g * 4 + r] + v[r]) * inv);
                *(bf16v4*)&orow[mt * 32 + g * 8 + 4 * hh] = pk;
            }
    }
}

// ---------------------------------------------------------------------------
// launch
// ---------------------------------------------------------------------------
extern "C" void kernel_launch(void* const* d_in, const int* in_sizes, int n_in,
                              void* d_out, int out_size, void* d_ws, size_t ws_size,
                              hipStream_t stream) {
    const float* X   = (const float*)d_in[0];
    const float* Wq  = (const float*)d_in[1];
    const float* bq  = (const float*)d_in[2];
    const float* Wkv = (const float*)d_in[3];
    const float* bkv = (const float*)d_in[4];
    const float* Wo  = (const float*)d_in[5];
    const float* bo  = (const float*)d_in[6];
    float* out = (float*)d_out;

    char* ws = (char*)d_ws;
    bf16* Xbf   = (bf16*)(ws);                     // 8 MB  (4096x1024)
    bf16* WqkvT = (bf16*)(ws + (8ull << 20));      // 6 MB  (3072x1024)
    bf16* WoT   = (bf16*)(ws + (14ull << 20));     // 2 MB  (1024x1024)
    float* bqkv = (float*)(ws + (16ull << 20));    // 12 KB (3072)
    bf16* Qbf   = (bf16*)(ws + (17ull << 20));     // 8 MB (pre-scaled by CEXP)
    bf16* Kbf   = (bf16*)(ws + (25ull << 20));     // 8 MB
    bf16* VTbf  = (bf16*)(ws + (33ull << 20));     // 8 MB (per-head transposed V)
    bf16* Abf   = (bf16*)(ws + (41ull << 20));     // 8 MB

    // merged prep (1 launch)
    prep_kernel<<<8204, 256, 0, stream>>>(X, Wq, Wkv, Wo, bq, bkv, Xbf, WqkvT, WoT, bqkv);

    // fused QKV projection: (4096x1024) @ (1024x3072)
    gemm2_kernel<128, 128, 1><<<dim3(3072 / 128, MROWS / 128), 256, 0, stream>>>(
        Xbf, WqkvT, bqkv, Qbf, Kbf, VTbf, nullptr, 1024);

    // flash attention (XCD-swizzled linear grid, 64q blocks, khalf wave pairs)
    attn7_kernel<<<1024, 256, 0, stream>>>(Qbf, Kbf, VTbf, Abf);

    // output projection: (4096x1024) @ (1024x1024) + bo -> fp32
    gemm2_kernel<128, 64, 2><<<dim3(1024 / 64, MROWS / 128), 256, 0, stream>>>(
        Abf, WoT, bo, nullptr, nullptr, nullptr, out, 1024);
}